// Round 1
// baseline (30.200 us; speedup 1.0000x reference)
//
#include <hip/hip_runtime.h>

#define NN 64
#define KK 64
#define BETA_C 0.9f

// ---------------- Phase 1: g1 = graph @ W  ([8192,64] @ [64,64]) ----------------
__global__ __launch_bounds__(256) void g1_kernel(const float* __restrict__ graph,
                                                 const float* __restrict__ W,
                                                 float* __restrict__ g1) {
    __shared__ float Ws[KK][KK];          // Ws[k][l]
    int t = threadIdx.x;
    for (int idx = t; idx < KK * KK; idx += 256)
        Ws[idx >> 6][idx & 63] = W[idx];
    __syncthreads();

    int lane = t & 63;                    // output col l
    int row  = blockIdx.x * 4 + (t >> 6); // 4 rows per block
    const float* a = graph + (size_t)row * KK;
    float acc = 0.f;
#pragma unroll
    for (int k = 0; k < KK; ++k)
        acc = fmaf(a[k], Ws[k][lane], acc);
    g1[(size_t)row * KK + lane] = acc;
}

// ---------------- Phase 2: walk + mask + relu-sum + lerp ----------------
// One 64-lane wave per (b,i,m). lane = k.
__global__ __launch_bounds__(64) void walk_kernel(const float* __restrict__ graph,
                                                  const float* __restrict__ g1,
                                                  const int* __restrict__ mask,
                                                  float* __restrict__ out) {
    int bid = blockIdx.x;
    int m = bid & 63;
    int i = (bid >> 6) & 63;
    int b = bid >> 12;
    int lane = threadIdx.x;               // k; doubles as j for mask staging

    // mask_[b,i,j=lane,m]
    int mv = mask[(((size_t)(b * NN + i)) * NN + lane) * NN + m];
    bool vj = (mv != 0) && (lane != m) && (lane != i);
    unsigned long long vm = __ballot(vj); // bit j set iff j is a valid walk step
    if (i == m) vm = 0ULL;

    const float* g1row = g1 + ((size_t)(b * NN + i)) * NN * KK;       // + j*KK + k
    const float* gcol  = graph + ((size_t)b * NN * NN + m) * KK;      // + j*NN*KK + k

    float acc = 0.f;
    bool anynz = false;
    while (vm) {
        int j = __builtin_ctzll(vm);
        vm &= vm - 1;
        float p = g1row[j * KK + lane] * gcol[(size_t)j * NN * KK + lane];
        anynz |= (p != 0.f);
        acc += fmaxf(p, 0.f);
    }

    size_t o = (((size_t)(b * NN + i)) * NN + m) * KK + lane;
    float old = graph[o];
    float beta = anynz ? BETA_C : 1.0f;
    out[o] = acc + beta * (old - acc);
}

// ---------------- Fallback (only if ws too small): recompute g1 per block ----------------
__global__ __launch_bounds__(64) void walk_fused_kernel(const float* __restrict__ graph,
                                                        const float* __restrict__ W,
                                                        const int* __restrict__ mask,
                                                        float* __restrict__ out) {
    __shared__ float Ws[KK][KK];
    __shared__ float g1s[NN][KK];
    int bid = blockIdx.x;
    int m = bid & 63;
    int i = (bid >> 6) & 63;
    int b = bid >> 12;
    int lane = threadIdx.x;

    for (int idx = lane; idx < KK * KK; idx += 64)
        Ws[idx >> 6][idx & 63] = W[idx];
    __syncthreads();

    const float* arow = graph + ((size_t)(b * NN + i)) * NN * KK;
    for (int j = 0; j < NN; ++j) {
        float acc = 0.f;
#pragma unroll
        for (int kk2 = 0; kk2 < KK; ++kk2)
            acc = fmaf(arow[j * KK + kk2], Ws[kk2][lane], acc);
        g1s[j][lane] = acc;
    }
    __syncthreads();

    int mv = mask[(((size_t)(b * NN + i)) * NN + lane) * NN + m];
    bool vj = (mv != 0) && (lane != m) && (lane != i);
    unsigned long long vm = __ballot(vj);
    if (i == m) vm = 0ULL;

    const float* gcol = graph + ((size_t)b * NN * NN + m) * KK;
    float acc = 0.f;
    bool anynz = false;
    while (vm) {
        int j = __builtin_ctzll(vm);
        vm &= vm - 1;
        float p = g1s[j][lane] * gcol[(size_t)j * NN * KK + lane];
        anynz |= (p != 0.f);
        acc += fmaxf(p, 0.f);
    }

    size_t o = (((size_t)(b * NN + i)) * NN + m) * KK + lane;
    float old = graph[o];
    float beta = anynz ? BETA_C : 1.0f;
    out[o] = acc + beta * (old - acc);
}

extern "C" void kernel_launch(void* const* d_in, const int* in_sizes, int n_in,
                              void* d_out, int out_size, void* d_ws, size_t ws_size,
                              hipStream_t stream) {
    const float* graph = (const float*)d_in[0];
    const float* W     = (const float*)d_in[1];
    const int*   mask  = (const int*)d_in[2];
    float*       out   = (float*)d_out;

    int B = in_sizes[0] / (NN * NN * KK);     // 2
    int total = B * NN * NN;                  // 8192 (b,i,m) rows
    size_t g1_bytes = (size_t)in_sizes[0] * sizeof(float);

    if (ws_size >= g1_bytes) {
        float* g1 = (float*)d_ws;
        int rows = in_sizes[0] / KK;          // 8192
        g1_kernel<<<rows / 4, 256, 0, stream>>>(graph, W, g1);
        walk_kernel<<<total, 64, 0, stream>>>(graph, g1, mask, out);
    } else {
        walk_fused_kernel<<<total, 64, 0, stream>>>(graph, W, mask, out);
    }
}

// Round 2
// 26.284 us; speedup vs baseline: 1.1490x; 1.1490x over previous
//
#include <hip/hip_runtime.h>

#define NN 64
#define KK 64
#define BETA_C 0.9f

// ---------------- Phase 1: g1 = graph @ W  ([8192,64] @ [64,64]) ----------------
__global__ __launch_bounds__(256) void g1_kernel(const float* __restrict__ graph,
                                                 const float* __restrict__ W,
                                                 float* __restrict__ g1) {
    __shared__ float Ws[KK][KK];          // Ws[k][l]
    int t = threadIdx.x;
    for (int idx = t; idx < KK * KK; idx += 256)
        Ws[idx >> 6][idx & 63] = W[idx];
    __syncthreads();

    int lane = t & 63;                    // output col l
    int row  = blockIdx.x * 4 + (t >> 6); // 4 rows per block
    const float* a = graph + (size_t)row * KK;
    float acc = 0.f;
#pragma unroll
    for (int k = 0; k < KK; ++k)
        acc = fmaf(a[k], Ws[k][lane], acc);
    g1[(size_t)row * KK + lane] = acc;
}

// ---------------- Phase 2: walk + mask + relu-sum + lerp ----------------
// Block = (b, i, m-octet): 8 waves, wave w handles m = moct*8 + w. lane = k.
// g1[b,i,:,:] staged in LDS; gcol streamed from global (L2-resident);
// unconditional unrolled j-loop with bitmask select for full MLP.
__global__ __launch_bounds__(512) void walk_kernel(const float* __restrict__ graph,
                                                   const float* __restrict__ g1,
                                                   const int* __restrict__ mask,
                                                   float* __restrict__ out) {
    __shared__ float g1s[NN][KK];         // 16 KB

    int bid  = blockIdx.x;                // ((b*64 + i)*8 + moct)
    int moct = bid & 7;
    int i    = (bid >> 3) & 63;
    int b    = bid >> 9;
    int t    = threadIdx.x;
    int w    = t >> 6;                    // wave id 0..7
    int lane = t & 63;                    // k (doubles as j for mask ballot)
    int m    = moct * 8 + w;

    // stage g1[b,i,:,:] (4096 floats) coalesced as float4: 2 per thread
    {
        const float4* src = (const float4*)(g1 + ((size_t)(b * NN + i)) * NN * KK);
        float4* dst = (float4*)&g1s[0][0];
        dst[t]       = src[t];
        dst[t + 512] = src[t + 512];
    }
    __syncthreads();

    // validity bitmask over j (lane plays j here): mask_[b,i,j,m] && j!=m && j!=i
    int mv = mask[(((size_t)(b * NN + i)) * NN + lane) * NN + m];
    bool vj = (mv != 0) & (lane != m) & (lane != i);
    unsigned long long vm = __ballot(vj);
    if (i == m) vm = 0ULL;

    const float* gcol = graph + ((size_t)b * NN * NN + m) * KK + lane; // + j*NN*KK

    float acc = 0.f;
    bool anynz = false;
#pragma unroll 16
    for (int j = 0; j < NN; ++j) {
        float gv  = gcol[(size_t)j * NN * KK];
        float g1v = g1s[j][lane];
        float p   = gv * g1v;
        bool  v   = (vm >> j) & 1ULL;
        p = v ? p : 0.f;
        anynz |= (p != 0.f);
        acc += fmaxf(p, 0.f);
    }

    size_t o = (((size_t)(b * NN + i)) * NN + m) * KK + lane;
    float old = graph[o];
    float beta = anynz ? BETA_C : 1.0f;
    out[o] = acc + beta * (old - acc);
}

// ---------------- Fallback (only if ws too small): recompute g1 per block ----------------
__global__ __launch_bounds__(64) void walk_fused_kernel(const float* __restrict__ graph,
                                                        const float* __restrict__ W,
                                                        const int* __restrict__ mask,
                                                        float* __restrict__ out) {
    __shared__ float Ws[KK][KK];
    __shared__ float g1s[NN][KK];
    int bid = blockIdx.x;
    int m = bid & 63;
    int i = (bid >> 6) & 63;
    int b = bid >> 12;
    int lane = threadIdx.x;

    for (int idx = lane; idx < KK * KK; idx += 64)
        Ws[idx >> 6][idx & 63] = W[idx];
    __syncthreads();

    const float* arow = graph + ((size_t)(b * NN + i)) * NN * KK;
    for (int j = 0; j < NN; ++j) {
        float acc = 0.f;
#pragma unroll
        for (int kk2 = 0; kk2 < KK; ++kk2)
            acc = fmaf(arow[j * KK + kk2], Ws[kk2][lane], acc);
        g1s[j][lane] = acc;
    }
    __syncthreads();

    int mv = mask[(((size_t)(b * NN + i)) * NN + lane) * NN + m];
    bool vj = (mv != 0) && (lane != m) && (lane != i);
    unsigned long long vm = __ballot(vj);
    if (i == m) vm = 0ULL;

    const float* gcol = graph + ((size_t)b * NN * NN + m) * KK;
    float acc = 0.f;
    bool anynz = false;
    while (vm) {
        int j = __builtin_ctzll(vm);
        vm &= vm - 1;
        float p = g1s[j][lane] * gcol[(size_t)j * NN * KK + lane];
        anynz |= (p != 0.f);
        acc += fmaxf(p, 0.f);
    }

    size_t o = (((size_t)(b * NN + i)) * NN + m) * KK + lane;
    float old = graph[o];
    float beta = anynz ? BETA_C : 1.0f;
    out[o] = acc + beta * (old - acc);
}

extern "C" void kernel_launch(void* const* d_in, const int* in_sizes, int n_in,
                              void* d_out, int out_size, void* d_ws, size_t ws_size,
                              hipStream_t stream) {
    const float* graph = (const float*)d_in[0];
    const float* W     = (const float*)d_in[1];
    const int*   mask  = (const int*)d_in[2];
    float*       out   = (float*)d_out;

    int B = in_sizes[0] / (NN * NN * KK);     // 2
    size_t g1_bytes = (size_t)in_sizes[0] * sizeof(float);

    if (ws_size >= g1_bytes) {
        float* g1 = (float*)d_ws;
        int rows = in_sizes[0] / KK;          // 8192
        g1_kernel<<<rows / 4, 256, 0, stream>>>(graph, W, g1);
        walk_kernel<<<B * NN * 8, 512, 0, stream>>>(graph, g1, mask, out);
    } else {
        walk_fused_kernel<<<B * NN * NN, 64, 0, stream>>>(graph, W, mask, out);
    }
}

// Round 3
// 23.812 us; speedup vs baseline: 1.2683x; 1.1038x over previous
//
#include <hip/hip_runtime.h>

#define NN 64
#define KK 64
#define BETA_C 0.9f

// ---------------- Phase 1: g1 = graph @ W  ([8192,64] @ [64,64]) ----------------
// 256 threads = 4 waves; each wave computes 2 rows (shares Ws ds_reads across rows).
__global__ __launch_bounds__(256) void g1_kernel(const float* __restrict__ graph,
                                                 const float* __restrict__ W,
                                                 float* __restrict__ g1) {
    __shared__ float Ws[KK][KK];          // Ws[k][l]
    int t = threadIdx.x;
    for (int idx = t; idx < KK * KK; idx += 256)
        Ws[idx >> 6][idx & 63] = W[idx];
    __syncthreads();

    int lane = t & 63;                    // output col l
    int w    = t >> 6;
    int row0 = blockIdx.x * 8 + w * 2;    // 8 rows per block, 2 per wave
    const float4* a0 = (const float4*)(graph + (size_t)row0 * KK);
    const float4* a1 = (const float4*)(graph + (size_t)(row0 + 1) * KK);
    float acc0 = 0.f, acc1 = 0.f;
#pragma unroll
    for (int k4 = 0; k4 < 16; ++k4) {
        float4 x0 = a0[k4];
        float4 x1 = a1[k4];
        float w0 = Ws[4 * k4 + 0][lane];
        float w1 = Ws[4 * k4 + 1][lane];
        float w2 = Ws[4 * k4 + 2][lane];
        float w3 = Ws[4 * k4 + 3][lane];
        acc0 = fmaf(x0.x, w0, acc0); acc1 = fmaf(x1.x, w0, acc1);
        acc0 = fmaf(x0.y, w1, acc0); acc1 = fmaf(x1.y, w1, acc1);
        acc0 = fmaf(x0.z, w2, acc0); acc1 = fmaf(x1.z, w2, acc1);
        acc0 = fmaf(x0.w, w3, acc0); acc1 = fmaf(x1.w, w3, acc1);
    }
    g1[(size_t)row0 * KK + lane]       = acc0;
    g1[(size_t)(row0 + 1) * KK + lane] = acc1;
}

// ---------------- Phase 2: walk + mask + relu-sum + lerp ----------------
// Block = (b, i, m-octet): 8 waves, wave w -> m = moct*8 + w. lane = k.
// g1[b,i,:,:] and mask[b,i,:,m-octet] staged in LDS (coalesced).
// Sparse iteration over valid j: SGPR bitmask, batches of 8 extracted in SALU.
__global__ __launch_bounds__(512) void walk_kernel(const float* __restrict__ graph,
                                                   const float* __restrict__ g1,
                                                   const int* __restrict__ mask,
                                                   float* __restrict__ out) {
    __shared__ float g1s[NN][KK];         // 16 KB
    __shared__ int   ms[NN][9];           // 2.25 KB, pad 9: gcd(9,32)=1 -> conflict-free

    int bid  = blockIdx.x;                // ((b*64 + i)*8 + moct)
    int moct = bid & 7;
    int i    = (bid >> 3) & 63;
    int b    = bid >> 9;
    int t    = threadIdx.x;
    int w    = t >> 6;                    // wave id 0..7
    int lane = t & 63;                    // k (doubles as j for ballot)
    int m0   = moct * 8;
    int m    = m0 + w;

    // stage g1[b,i,:,:] (4096 floats) coalesced as float4
    {
        const float4* src = (const float4*)(g1 + ((size_t)(b * NN + i)) * NN * KK);
        float4* dst = (float4*)&g1s[0][0];
        dst[t]       = src[t];
        dst[t + 512] = src[t + 512];
    }
    // stage mask[b,i,:,m0:m0+8]: thread t -> (j = t>>3, c = t&7), 32B chunks
    {
        int j = t >> 3, c = t & 7;
        ms[j][c] = mask[(((size_t)(b * NN + i)) * NN + j) * NN + m0 + c];
    }
    __syncthreads();

    bool vj = (ms[lane][w] != 0) & (lane != m) & (lane != i);
    unsigned long long vm = __ballot(vj);
    if (i == m) vm = 0ULL;

    const float* gcol = graph + ((size_t)b * NN * NN + m) * KK + lane; // + j*NN*KK

    float acc2 = 0.f, absacc = 0.f;
    while (vm) {
        unsigned long long tv = vm;
        int  jj[8];
        bool lv[8];
#pragma unroll
        for (int n = 0; n < 8; ++n) {
            lv[n] = (tv != 0ULL);
            jj[n] = (int)__builtin_ctzll(lv[n] ? tv : 1ULL);  // 0 when dead
            tv &= tv - 1ULL;                                   // 0 stays 0
        }
        vm = tv;
        float gv[8], gw[8];
#pragma unroll
        for (int n = 0; n < 8; ++n) {
            gv[n] = gcol[(size_t)jj[n] * (NN * KK)];
            gw[n] = g1s[jj[n]][lane];
        }
#pragma unroll
        for (int n = 0; n < 8; ++n) {
            float p = lv[n] ? gv[n] * gw[n] : 0.f;
            acc2   += p;
            absacc += fabsf(p);
        }
    }

    size_t o   = (((size_t)(b * NN + i)) * NN + m) * KK + lane;
    float old  = graph[o];
    float nw   = (acc2 + absacc) * 0.5f;          // == sum(relu(p)) exactly in reals
    float beta = (absacc != 0.f) ? BETA_C : 1.0f; // anynz <=> sum|p| != 0
    out[o] = nw + beta * (old - nw);
}

// ---------------- Fallback (only if ws too small): recompute g1 per block ----------------
__global__ __launch_bounds__(64) void walk_fused_kernel(const float* __restrict__ graph,
                                                        const float* __restrict__ W,
                                                        const int* __restrict__ mask,
                                                        float* __restrict__ out) {
    __shared__ float Ws[KK][KK];
    __shared__ float g1s[NN][KK];
    int bid = blockIdx.x;
    int m = bid & 63;
    int i = (bid >> 6) & 63;
    int b = bid >> 12;
    int lane = threadIdx.x;

    for (int idx = lane; idx < KK * KK; idx += 64)
        Ws[idx >> 6][idx & 63] = W[idx];
    __syncthreads();

    const float* arow = graph + ((size_t)(b * NN + i)) * NN * KK;
    for (int j = 0; j < NN; ++j) {
        float acc = 0.f;
#pragma unroll
        for (int kk2 = 0; kk2 < KK; ++kk2)
            acc = fmaf(arow[j * KK + kk2], Ws[kk2][lane], acc);
        g1s[j][lane] = acc;
    }
    __syncthreads();

    int mv = mask[(((size_t)(b * NN + i)) * NN + lane) * NN + m];
    bool vj = (mv != 0) && (lane != m) && (lane != i);
    unsigned long long vm = __ballot(vj);
    if (i == m) vm = 0ULL;

    const float* gcol = graph + ((size_t)b * NN * NN + m) * KK;
    float acc = 0.f;
    bool anynz = false;
    while (vm) {
        int j = __builtin_ctzll(vm);
        vm &= vm - 1;
        float p = g1s[j][lane] * gcol[(size_t)j * NN * KK + lane];
        anynz |= (p != 0.f);
        acc += fmaxf(p, 0.f);
    }

    size_t o = (((size_t)(b * NN + i)) * NN + m) * KK + lane;
    float old = graph[o];
    float beta = anynz ? BETA_C : 1.0f;
    out[o] = acc + beta * (old - acc);
}

extern "C" void kernel_launch(void* const* d_in, const int* in_sizes, int n_in,
                              void* d_out, int out_size, void* d_ws, size_t ws_size,
                              hipStream_t stream) {
    const float* graph = (const float*)d_in[0];
    const float* W     = (const float*)d_in[1];
    const int*   mask  = (const int*)d_in[2];
    float*       out   = (float*)d_out;

    int B = in_sizes[0] / (NN * NN * KK);     // 2
    size_t g1_bytes = (size_t)in_sizes[0] * sizeof(float);

    if (ws_size >= g1_bytes) {
        float* g1 = (float*)d_ws;
        int rows = in_sizes[0] / KK;          // 8192
        g1_kernel<<<rows / 8, 256, 0, stream>>>(graph, W, g1);
        walk_kernel<<<B * NN * 8, 512, 0, stream>>>(graph, g1, mask, out);
    } else {
        walk_fused_kernel<<<B * NN * NN, 64, 0, stream>>>(graph, W, mask, out);
    }
}

// Round 4
// 22.155 us; speedup vs baseline: 1.3631x; 1.0748x over previous
//
#include <hip/hip_runtime.h>

#define NN 64
#define KK 64
#define BETA_C 0.9f

// ---------------- Phase 1: g1 = graph @ W  ([8192,64] @ [64,64]) ----------------
// 256 threads = 4 waves; each wave computes 4 rows (shares Ws ds_reads across 4 rows).
__global__ __launch_bounds__(256) void g1_kernel(const float* __restrict__ graph,
                                                 const float* __restrict__ W,
                                                 float* __restrict__ g1) {
    __shared__ float Ws[KK][KK];          // Ws[k][l]
    int t = threadIdx.x;
    for (int idx = t; idx < KK * KK; idx += 256)
        Ws[idx >> 6][idx & 63] = W[idx];
    __syncthreads();

    int lane = t & 63;                           // output col l
    int w    = __builtin_amdgcn_readfirstlane(t >> 6);
    int r0   = blockIdx.x * 16 + w * 4;          // 16 rows/block, 4 per wave
    const float4* a = (const float4*)(graph + (size_t)r0 * KK);  // 16 float4 per row
    float acc0 = 0.f, acc1 = 0.f, acc2 = 0.f, acc3 = 0.f;
#pragma unroll
    for (int k4 = 0; k4 < 16; ++k4) {
        float4 x0 = a[k4];
        float4 x1 = a[k4 + 16];
        float4 x2 = a[k4 + 32];
        float4 x3 = a[k4 + 48];
        float w0 = Ws[4 * k4 + 0][lane];
        float w1 = Ws[4 * k4 + 1][lane];
        float w2 = Ws[4 * k4 + 2][lane];
        float w3 = Ws[4 * k4 + 3][lane];
        acc0 = fmaf(x0.x, w0, acc0); acc1 = fmaf(x1.x, w0, acc1);
        acc2 = fmaf(x2.x, w0, acc2); acc3 = fmaf(x3.x, w0, acc3);
        acc0 = fmaf(x0.y, w1, acc0); acc1 = fmaf(x1.y, w1, acc1);
        acc2 = fmaf(x2.y, w1, acc2); acc3 = fmaf(x3.y, w1, acc3);
        acc0 = fmaf(x0.z, w2, acc0); acc1 = fmaf(x1.z, w2, acc1);
        acc2 = fmaf(x2.z, w2, acc2); acc3 = fmaf(x3.z, w2, acc3);
        acc0 = fmaf(x0.w, w3, acc0); acc1 = fmaf(x1.w, w3, acc1);
        acc2 = fmaf(x2.w, w3, acc2); acc3 = fmaf(x3.w, w3, acc3);
    }
    g1[(size_t)(r0 + 0) * KK + lane] = acc0;
    g1[(size_t)(r0 + 1) * KK + lane] = acc1;
    g1[(size_t)(r0 + 2) * KK + lane] = acc2;
    g1[(size_t)(r0 + 3) * KK + lane] = acc3;
}

// ---------------- Phase 2: walk + mask + relu-sum + lerp ----------------
// Block = (b, i, m-octet): 8 waves, wave w -> m = moct*8 + w (w forced SGPR via
// readfirstlane so vm / jj / batch extraction stay fully scalar). lane = k.
__global__ __launch_bounds__(512, 8) void walk_kernel(const float* __restrict__ graph,
                                                      const float* __restrict__ g1,
                                                      const int* __restrict__ mask,
                                                      float* __restrict__ out) {
    __shared__ float g1s[NN][KK];         // 16 KB
    __shared__ int   ms[NN][9];           // pad 9: gcd(9,32)=1 -> <=2-way (free)

    int bid  = blockIdx.x;                // ((b*64 + i)*8 + moct)
    int moct = bid & 7;
    int i    = (bid >> 3) & 63;
    int b    = bid >> 9;
    int t    = threadIdx.x;
    int lane = t & 63;                    // k (doubles as j for ballot)
    int w    = __builtin_amdgcn_readfirstlane(t >> 6);  // wave id, provably uniform
    int m    = moct * 8 + w;              // SGPR

    // stage g1[b,i,:,:] (4096 floats) coalesced as float4
    {
        const float4* src = (const float4*)(g1 + ((size_t)(b * NN + i)) * NN * KK);
        float4* dst = (float4*)&g1s[0][0];
        dst[t]       = src[t];
        dst[t + 512] = src[t + 512];
    }
    // stage mask[b,i,:,m0:m0+8]: thread t -> (j = t>>3, c = t&7)
    {
        int j = t >> 3, c = t & 7;
        ms[j][c] = mask[(((size_t)(b * NN + i)) * NN + j) * NN + moct * 8 + c];
    }
    __syncthreads();

    bool vj = (ms[lane][w] != 0) & (lane != m) & (lane != i);
    unsigned long long vm = __ballot(vj);         // SGPR pair
    if (i == m) vm = 0ULL;                        // scalar select now

    const float* gbase = graph + ((size_t)b * NN * NN + m) * KK;  // SGPR base

    float acc2 = 0.f, absacc = 0.f;
    while (vm) {
        unsigned long long tv = vm;
        int  jj[8];
        bool lv[8];
#pragma unroll
        for (int n = 0; n < 8; ++n) {
            lv[n] = (tv != 0ULL);
            jj[n] = (int)__builtin_ctzll(lv[n] ? tv : 1ULL);  // 0 when dead (scalar)
            tv &= tv - 1ULL;
        }
        vm = tv;
        float gv[8], gw[8];
#pragma unroll
        for (int n = 0; n < 8; ++n) {
            const float* pj = gbase + (size_t)jj[n] * (NN * KK); // SGPR pointer -> saddr
            gv[n] = pj[lane];
            gw[n] = g1s[jj[n]][lane];
        }
#pragma unroll
        for (int n = 0; n < 8; ++n) {
            float p = lv[n] ? gv[n] * gw[n] : 0.f;
            acc2   += p;
            absacc += fabsf(p);
        }
    }

    size_t o   = (((size_t)(b * NN + i)) * NN + m) * KK + lane;
    float old  = graph[o];
    float nw   = (acc2 + absacc) * 0.5f;          // == sum(relu(p)) exactly
    float beta = (absacc != 0.f) ? BETA_C : 1.0f; // anynz <=> sum|p| != 0
    out[o] = nw + beta * (old - nw);
}

// ---------------- Fallback (only if ws too small): recompute g1 per block ----------------
__global__ __launch_bounds__(64) void walk_fused_kernel(const float* __restrict__ graph,
                                                        const float* __restrict__ W,
                                                        const int* __restrict__ mask,
                                                        float* __restrict__ out) {
    __shared__ float Ws[KK][KK];
    __shared__ float g1s[NN][KK];
    int bid = blockIdx.x;
    int m = bid & 63;
    int i = (bid >> 6) & 63;
    int b = bid >> 12;
    int lane = threadIdx.x;

    for (int idx = lane; idx < KK * KK; idx += 64)
        Ws[idx >> 6][idx & 63] = W[idx];
    __syncthreads();

    const float* arow = graph + ((size_t)(b * NN + i)) * NN * KK;
    for (int j = 0; j < NN; ++j) {
        float acc = 0.f;
#pragma unroll
        for (int kk2 = 0; kk2 < KK; ++kk2)
            acc = fmaf(arow[j * KK + kk2], Ws[kk2][lane], acc);
        g1s[j][lane] = acc;
    }
    __syncthreads();

    int mv = mask[(((size_t)(b * NN + i)) * NN + lane) * NN + m];
    bool vj = (mv != 0) && (lane != m) && (lane != i);
    unsigned long long vm = __ballot(vj);
    if (i == m) vm = 0ULL;

    const float* gcol = graph + ((size_t)b * NN * NN + m) * KK;
    float acc = 0.f;
    bool anynz = false;
    while (vm) {
        int j = __builtin_ctzll(vm);
        vm &= vm - 1;
        float p = g1s[j][lane] * gcol[(size_t)j * NN * KK + lane];
        anynz |= (p != 0.f);
        acc += fmaxf(p, 0.f);
    }

    size_t o = (((size_t)(b * NN + i)) * NN + m) * KK + lane;
    float old = graph[o];
    float beta = anynz ? BETA_C : 1.0f;
    out[o] = acc + beta * (old - acc);
}

extern "C" void kernel_launch(void* const* d_in, const int* in_sizes, int n_in,
                              void* d_out, int out_size, void* d_ws, size_t ws_size,
                              hipStream_t stream) {
    const float* graph = (const float*)d_in[0];
    const float* W     = (const float*)d_in[1];
    const int*   mask  = (const int*)d_in[2];
    float*       out   = (float*)d_out;

    int B = in_sizes[0] / (NN * NN * KK);     // 2
    size_t g1_bytes = (size_t)in_sizes[0] * sizeof(float);

    if (ws_size >= g1_bytes) {
        float* g1 = (float*)d_ws;
        int rows = in_sizes[0] / KK;          // 8192
        g1_kernel<<<rows / 16, 256, 0, stream>>>(graph, W, g1);
        walk_kernel<<<B * NN * 8, 512, 0, stream>>>(graph, g1, mask, out);
    } else {
        walk_fused_kernel<<<B * NN * NN, 64, 0, stream>>>(graph, W, mask, out);
    }
}

// Round 5
// 18.972 us; speedup vs baseline: 1.5918x; 1.1678x over previous
//
#include <hip/hip_runtime.h>

#define NN 64
#define KK 64
#define BETA_C 0.9f

// Single fused kernel. Block = (b, i, m-half). 1024 threads = 16 waves.
// Phase A: stage W + mask slice; waves 0..7 compute g1[b,i,:,:] -> LDS (8 rows/wave).
// Phase B: wave w walks m0 = mh*32 + 2w and m1 = m0+1 over the union validity mask.
__global__ __launch_bounds__(1024, 4) void walk_fused1(const float* __restrict__ graph,
                                                       const float* __restrict__ W,
                                                       const int* __restrict__ mask,
                                                       float* __restrict__ out) {
    __shared__ float Ws[KK][KK];    // 16 KB, Ws[k][l]
    __shared__ float g1s[NN][KK];   // 16 KB
    __shared__ int   ms[NN][33];    // 8.25 KB, pad 33 -> <=2-way (free)

    int bid = blockIdx.x;
    int b, i, mh;
    if (gridDim.x == 256) {
        // XCD-clustered decode: blocks with same (b, mh, i-half) share bid%8 -> same XCD;
        // their gcol working set graph[b, :, mh-half, :] = 4 MB = one XCD L2.
        int xcdsel = bid & 7;
        b  = xcdsel >> 2;
        mh = (xcdsel >> 1) & 1;
        i  = ((xcdsel & 1) << 5) | (bid >> 3);
    } else {
        mh = bid & 1;
        i  = (bid >> 1) & 63;
        b  = bid >> 7;
    }

    int t    = threadIdx.x;
    int lane = t & 63;                                   // k (doubles as j for ballot)
    int w    = __builtin_amdgcn_readfirstlane(t >> 6);   // wave id 0..15, provably SGPR

    size_t biBase = (size_t)(b * NN + i);

    // ---- stage W (one float4 per thread) ----
    ((float4*)&Ws[0][0])[t] = ((const float4*)W)[t];

    // ---- stage mask[b,i,:,mh*32 .. mh*32+31] (2 ints per thread) ----
    {
        const int* mbase = mask + (biBase * NN) * NN + mh * 32;
        int j = t >> 5, c = t & 31;
        ms[j][c]      = mbase[(size_t)j * NN + c];
        ms[j + 32][c] = mbase[(size_t)(j + 32) * NN + c];
    }
    __syncthreads();

    // ---- Phase A: GEMM g1s = graph[b,i,:,:] @ W, waves 0..7, 8 rows each ----
    if (w < 8) {
        int r0 = w * 8;
        const float4* a = (const float4*)(graph + (biBase * NN + r0) * KK); // 16 f4/row
        float acc[8] = {0.f, 0.f, 0.f, 0.f, 0.f, 0.f, 0.f, 0.f};
#pragma unroll
        for (int k4 = 0; k4 < 16; ++k4) {
            float4 x[8];
#pragma unroll
            for (int r = 0; r < 8; ++r) x[r] = a[k4 + 16 * r];   // broadcast loads
            float w0 = Ws[4 * k4 + 0][lane];
            float w1 = Ws[4 * k4 + 1][lane];
            float w2 = Ws[4 * k4 + 2][lane];
            float w3 = Ws[4 * k4 + 3][lane];
#pragma unroll
            for (int r = 0; r < 8; ++r) {
                acc[r] = fmaf(x[r].x, w0, acc[r]);
                acc[r] = fmaf(x[r].y, w1, acc[r]);
                acc[r] = fmaf(x[r].z, w2, acc[r]);
                acc[r] = fmaf(x[r].w, w3, acc[r]);
            }
        }
#pragma unroll
        for (int r = 0; r < 8; ++r) g1s[r0 + r][lane] = acc[r];
    }
    __syncthreads();

    // ---- Phase B: walk two m's per wave over the union bitmask ----
    int m0 = mh * 32 + 2 * w;
    int m1 = m0 + 1;

    bool v0 = (ms[lane][2 * w + 0] != 0) & (lane != m0) & (lane != i);
    bool v1 = (ms[lane][2 * w + 1] != 0) & (lane != m1) & (lane != i);
    unsigned long long vm0 = __ballot(v0);
    unsigned long long vm1 = __ballot(v1);
    if (i == m0) vm0 = 0ULL;
    if (i == m1) vm1 = 0ULL;
    unsigned long long vmU = vm0 | vm1;

    const float* gb0 = graph + ((size_t)b * NN * NN + m0) * KK;  // SGPR bases -> saddr
    const float* gb1 = graph + ((size_t)b * NN * NN + m1) * KK;

    float a0 = 0.f, s0 = 0.f, a1 = 0.f, s1 = 0.f;
    while (vmU) {
        unsigned long long tv = vmU;
        int  jj[8];
        bool lv[8];
#pragma unroll
        for (int n = 0; n < 8; ++n) {
            lv[n] = (tv != 0ULL);
            jj[n] = (int)__builtin_ctzll(lv[n] ? tv : 1ULL);   // scalar, 0 when dead
            tv &= tv - 1ULL;
        }
        vmU = tv;
        float gv0[8], gv1[8], gw[8];
#pragma unroll
        for (int n = 0; n < 8; ++n) {
            gv0[n] = gb0[(size_t)jj[n] * (NN * KK) + lane];
            gv1[n] = gb1[(size_t)jj[n] * (NN * KK) + lane];
            gw[n]  = g1s[jj[n]][lane];                          // shared by both m's
        }
#pragma unroll
        for (int n = 0; n < 8; ++n) {
            bool c0 = lv[n] && (((vm0 >> jj[n]) & 1ULL) != 0ULL);
            bool c1 = lv[n] && (((vm1 >> jj[n]) & 1ULL) != 0ULL);
            float p0 = c0 ? gv0[n] * gw[n] : 0.f;
            float p1 = c1 ? gv1[n] * gw[n] : 0.f;
            a0 += p0; s0 += fabsf(p0);
            a1 += p1; s1 += fabsf(p1);
        }
    }

    // ---- epilogue: lerp with beta ----
    {
        size_t o0 = (biBase * NN + m0) * KK + lane;
        size_t o1 = (biBase * NN + m1) * KK + lane;
        float old0 = graph[o0];
        float old1 = graph[o1];
        float nw0 = (a0 + s0) * 0.5f;                 // == sum(relu(p)) exactly
        float nw1 = (a1 + s1) * 0.5f;
        float be0 = (s0 != 0.f) ? BETA_C : 1.0f;      // anynz <=> sum|p| != 0
        float be1 = (s1 != 0.f) ? BETA_C : 1.0f;
        out[o0] = nw0 + be0 * (old0 - nw0);
        out[o1] = nw1 + be1 * (old1 - nw1);
    }
}

extern "C" void kernel_launch(void* const* d_in, const int* in_sizes, int n_in,
                              void* d_out, int out_size, void* d_ws, size_t ws_size,
                              hipStream_t stream) {
    const float* graph = (const float*)d_in[0];
    const float* W     = (const float*)d_in[1];
    const int*   mask  = (const int*)d_in[2];
    float*       out   = (float*)d_out;

    int B = in_sizes[0] / (NN * NN * KK);     // 2
    walk_fused1<<<B * NN * 2, 1024, 0, stream>>>(graph, W, mask, out);
}